// Round 6
// baseline (236.470 us; speedup 1.0000x reference)
//
#include <hip/hip_runtime.h>
#include <math.h>

#define NN 20000
#define EE 320000
#define ETOT 340000
#define GG 64
#define INCH 128
#define HIDC 64
#define NH 8
#define HC 512            // NH*HIDC
#define SLOPE 0.2f
#define SMEPS 1e-16f

typedef unsigned short u16;
typedef unsigned int u32;
typedef __attribute__((ext_vector_type(8))) short bf16x8;
typedef __attribute__((ext_vector_type(4))) float f32x4;
typedef __attribute__((ext_vector_type(4))) u32 u32x4;

__device__ __forceinline__ u16 f2bf(float f) {   // round-to-nearest-even
  u32 x = __float_as_uint(f);
  x += 0x7FFFu + ((x >> 16) & 1u);
  return (u16)(x >> 16);
}
__device__ __forceinline__ float bflo(u32 w) { return __uint_as_float(w << 16); }
__device__ __forceinline__ float bfhi(u32 w) { return __uint_as_float(w & 0xffff0000u); }

// ---------------- CSR build ----------------
__global__ void k_hist(const int* __restrict__ ei, int* __restrict__ deg) {
  int i = blockIdx.x * 256 + threadIdx.x;
  if (i >= ETOT) return;
  int d = (i < EE) ? ei[EE + i] : (i - EE);
  atomicAdd(&deg[d], 1);
}

__global__ void k_scan(const int* __restrict__ deg, int* __restrict__ rowstart) {
  __shared__ int wsum[16];
  __shared__ int carry_sh;
  int tid = threadIdx.x;
  int lane = tid & 63, w = tid >> 6;
  if (tid == 0) { carry_sh = 0; rowstart[0] = 0; }
  __syncthreads();
  for (int base = 0; base < NN; base += 1024) {
    int v = (base + tid < NN) ? deg[base + tid] : 0;
    int s = v;
#pragma unroll
    for (int off = 1; off < 64; off <<= 1) {
      int t = __shfl_up(s, off);
      if (lane >= off) s += t;
    }
    if (lane == 63) wsum[w] = s;
    __syncthreads();
    if (w == 0 && lane < 16) {
      int t = wsum[lane];
#pragma unroll
      for (int off = 1; off < 16; off <<= 1) {
        int u = __shfl_up(t, off);
        if (lane >= off) t += u;
      }
      wsum[lane] = t;
    }
    __syncthreads();
    int waveoff = (w == 0) ? 0 : wsum[w - 1];
    int incl = s + waveoff + carry_sh;
    if (base + tid < NN) rowstart[base + tid + 1] = incl;
    __syncthreads();
    if (tid == 1023) carry_sh = incl;
    __syncthreads();
  }
}

__global__ void k_fill(const int* __restrict__ ei, const int* __restrict__ rowstart,
                       int* __restrict__ wcur, int* __restrict__ csr) {
  int i = blockIdx.x * 256 + threadIdx.x;
  if (i >= ETOT) return;
  int s, d;
  if (i < EE) { s = ei[i]; d = ei[EE + i]; } else { s = i - EE; d = s; }
  int pos = rowstart[d] + atomicAdd(&wcur[d], 1);
  csr[pos] = s;
}

// ---------------- prep: W1bf, W2bf, wB1, xbf ----------------
__global__ void k_prep(const float* __restrict__ W1, const float* __restrict__ W2,
                       const float* __restrict__ as1, const float* __restrict__ ad1v,
                       const float* __restrict__ x,
                       u16* __restrict__ W1bf, u16* __restrict__ W2bf,
                       float* __restrict__ wB1, u16* __restrict__ xbf) {
  int i = blockIdx.x * 256 + threadIdx.x;
  if (i < 65536) {
    W1bf[i] = f2bf(W1[i]);
  } else if (i < 65536 + 32768) {
    int j = i - 65536;
    W2bf[j] = f2bf(W2[j]);
  } else if (i < 65536 + 32768 + 2048) {
    int j = i - 65536 - 32768;   // j = k*16 + c
    int k = j >> 4, c = j & 15;
    int h = c & 7;
    const float* av = (c < 8) ? as1 : ad1v;
    float s = 0.f;
    for (int q = 0; q < 64; ++q) s += W1[(h * 64 + q) * 128 + k] * av[h * 64 + q];
    wB1[j] = s;
  } else {
    int j = i - 100352;
    if (j < NN * INCH) xbf[j] = f2bf(x[j]);
  }
}

// ---------------- logits1: al1[n][0..7]=x@wS, [8..15]=x@wD (4 threads / row) ------------
__global__ __launch_bounds__(256) void k_logits1(
    const float* __restrict__ x, const float* __restrict__ wB1,
    float* __restrict__ al1) {
  __shared__ float bs[128][16];
  int tid = threadIdx.x;
#pragma unroll
  for (int i = 0; i < 8; ++i) {
    int e = tid + i * 256;
    bs[e >> 4][e & 15] = wB1[e];
  }
  __syncthreads();
  int gt = blockIdx.x * 256 + tid;
  int r = gt >> 2; if (r > NN - 1) r = NN - 1;
  int q = gt & 3;
  const float* xp = x + (size_t)r * INCH;
  float acc[4] = {0.f, 0.f, 0.f, 0.f};
  for (int kq = 0; kq < 32; ++kq) {
    float4 a = *(const float4*)(xp + kq * 4);
    float av[4] = {a.x, a.y, a.z, a.w};
#pragma unroll
    for (int kk = 0; kk < 4; ++kk) {
      const float4 b = *(const float4*)&bs[kq * 4 + kk][q * 4];
      acc[0] = fmaf(av[kk], b.x, acc[0]);
      acc[1] = fmaf(av[kk], b.y, acc[1]);
      acc[2] = fmaf(av[kk], b.z, acc[2]);
      acc[3] = fmaf(av[kk], b.w, acc[3]);
    }
  }
  float4 o; o.x = acc[0]; o.y = acc[1]; o.z = acc[2]; o.w = acc[3];
  *(float4*)(al1 + (size_t)r * 16 + q * 4) = o;
}

// ---------------- agg1: wave/node, 4-edge-parallel groups, bf16 x gather ----------------
// lane = e*16 + c : edge slot e (0..3), channel block c -> ch c*8..c*8+7
__global__ __launch_bounds__(256) void k_agg1(
    const u16* __restrict__ xbf, const float* __restrict__ al1,
    const int* __restrict__ rowstart, const int* __restrict__ csr,
    u16* __restrict__ aggbf) {
  int n = blockIdx.x * 4 + (threadIdx.x >> 6);
  int lane = threadIdx.x & 63;
  int e = lane >> 4, c = lane & 15;
  int rs = __builtin_amdgcn_readfirstlane(rowstart[n]);
  int re = __builtin_amdgcn_readfirstlane(rowstart[n + 1]);
  float4 ad0 = *(const float4*)(al1 + (size_t)n * 16 + 8);
  float4 ad1 = *(const float4*)(al1 + (size_t)n * 16 + 12);
  float acc[NH][8] = {};
  float zp[NH] = {};
  for (int base = rs; base < re; base += 4) {
    int idx = base + e;
    bool ok = idx < re;
    int s = csr[ok ? idx : re - 1];
    float4 a0 = *(const float4*)(al1 + (size_t)s * 16);
    float4 a1 = *(const float4*)(al1 + (size_t)s * 16 + 4);
    float ev[8] = {a0.x + ad0.x, a0.y + ad0.y, a0.z + ad0.z, a0.w + ad0.w,
                   a1.x + ad1.x, a1.y + ad1.y, a1.z + ad1.z, a1.w + ad1.w};
    float p[8];
#pragma unroll
    for (int h = 0; h < 8; ++h) {
      float t = ev[h]; t = (t > 0.f) ? t : SLOPE * t;
      float pv = __expf(t);
      p[h] = ok ? pv : 0.f;
      zp[h] += p[h];
    }
    u32x4 xw = *(const u32x4*)(xbf + (size_t)s * INCH + c * 8);
    float xf[8] = {bflo(xw.x), bfhi(xw.x), bflo(xw.y), bfhi(xw.y),
                   bflo(xw.z), bfhi(xw.z), bflo(xw.w), bfhi(xw.w)};
#pragma unroll
    for (int h = 0; h < 8; ++h) {
      float ph = p[h];
#pragma unroll
      for (int q = 0; q < 8; ++q) acc[h][q] = fmaf(ph, xf[q], acc[h][q]);
    }
  }
  // merge the 4 edge-slot partials (xor16 flips e bit0, xor32 flips e bit1)
#pragma unroll
  for (int h = 0; h < 8; ++h) {
    zp[h] += __shfl_xor(zp[h], 16); zp[h] += __shfl_xor(zp[h], 32);
#pragma unroll
    for (int q = 0; q < 8; ++q) {
      acc[h][q] += __shfl_xor(acc[h][q], 16);
      acc[h][q] += __shfl_xor(acc[h][q], 32);
    }
  }
  // group e writes heads 2e, 2e+1 (cndmask selects; no runtime array index)
  int e1 = e & 1, e2 = e & 2;
#pragma unroll
  for (int hh = 0; hh < 2; ++hh) {
    float za = e1 ? zp[2 + hh] : zp[0 + hh];
    float zb = e1 ? zp[6 + hh] : zp[4 + hh];
    float zz = e2 ? zb : za;
    float inv = 1.f / (zz + SMEPS);
    u32 pkv[4];
#pragma unroll
    for (int qq = 0; qq < 4; ++qq) {
      float val = e1 ? acc[2 + hh][qq * 2] : acc[0 + hh][qq * 2];
      float vbl = e1 ? acc[6 + hh][qq * 2] : acc[4 + hh][qq * 2];
      float vl = (e2 ? vbl : val) * inv;
      float vah = e1 ? acc[2 + hh][qq * 2 + 1] : acc[0 + hh][qq * 2 + 1];
      float vbh = e1 ? acc[6 + hh][qq * 2 + 1] : acc[4 + hh][qq * 2 + 1];
      float vh = (e2 ? vbh : vah) * inv;
      pkv[qq] = ((u32)f2bf(vh) << 16) | (u32)f2bf(vl);
    }
    u32x4 st; st.x = pkv[0]; st.y = pkv[1]; st.z = pkv[2]; st.w = pkv[3];
    *(u32x4*)(aggbf + (size_t)(e * 2 + hh) * NN * INCH + (size_t)n * INCH + c * 8) = st;
  }
}

// ---------------- gemm1h: xmid[:, h*64..] = relu(agg_h @ W1_h^T + b1), MFMA bf16 --------
__global__ __launch_bounds__(256) void k_gemm1h(
    const u16* __restrict__ aggbf, const u16* __restrict__ W1bf,
    const float* __restrict__ b1, u16* __restrict__ xmidbf) {
  int tid = threadIdx.x;
  int head = blockIdx.x & 7;
  int nb = blockIdx.x >> 3;
  int w = tid >> 6, l = tid & 63;
  int li = l & 15, hi = l >> 4;
  const u16* Ab = aggbf + (size_t)head * NN * INCH;
  const u16* Bb = W1bf + (size_t)head * 64 * INCH;

  bf16x8 Bf[4][4];   // [ks][ct]
#pragma unroll
  for (int ks = 0; ks < 4; ++ks)
#pragma unroll
    for (int ct = 0; ct < 4; ++ct)
      Bf[ks][ct] = *(const bf16x8*)(Bb + (size_t)(ct * 16 + li) * INCH + ks * 32 + hi * 8);

  int nA = nb * 64 + w * 16 + li; if (nA > NN - 1) nA = NN - 1;
  const u16* Ap = Ab + (size_t)nA * INCH + hi * 8;
  f32x4 acc[4] = {};
#pragma unroll
  for (int ks = 0; ks < 4; ++ks) {
    bf16x8 Af = *(const bf16x8*)(Ap + ks * 32);
#pragma unroll
    for (int ct = 0; ct < 4; ++ct)
      acc[ct] = __builtin_amdgcn_mfma_f32_16x16x32_bf16(Af, Bf[ks][ct], acc[ct], 0, 0, 0);
  }
#pragma unroll
  for (int ct = 0; ct < 4; ++ct) {
    float bb = b1[head * 64 + ct * 16 + li];
#pragma unroll
    for (int reg = 0; reg < 4; ++reg) {
      int r = nb * 64 + w * 16 + hi * 4 + reg; if (r > NN - 1) r = NN - 1;
      float v = fmaxf(acc[ct][reg] + bb, 0.f);
      xmidbf[(size_t)r * HC + head * 64 + ct * 16 + li] = f2bf(v);
    }
  }
}

// ---------------- gemm2: h2 = xmid @ W2^T (MFMA bf16, K split over 4 waves) + logits ----
__global__ __launch_bounds__(256) void k_gemm2(
    const u16* __restrict__ xmb, const u16* __restrict__ W2bf,
    const float* __restrict__ atts, const float* __restrict__ attd,
    u16* __restrict__ h2bf, float* __restrict__ as2, float* __restrict__ ad2) {
  __shared__ float red[4][16][65];
  int tid = threadIdx.x;
  int w = tid >> 6, l = tid & 63;
  int li = l & 15, hi = l >> 4;
  int brow = blockIdx.x * 16;     // 1250 blocks * 16 = 20000 exact

  bf16x8 Bf[4][4];
#pragma unroll
  for (int ksl = 0; ksl < 4; ++ksl)
#pragma unroll
    for (int ct = 0; ct < 4; ++ct)
      Bf[ksl][ct] = *(const bf16x8*)(W2bf + (size_t)(ct * 16 + li) * HC + w * 128 + ksl * 32 + hi * 8);

  const u16* Ap = xmb + (size_t)(brow + li) * HC + w * 128 + hi * 8;
  f32x4 acc[4] = {};
#pragma unroll
  for (int ksl = 0; ksl < 4; ++ksl) {
    bf16x8 Af = *(const bf16x8*)(Ap + ksl * 32);
#pragma unroll
    for (int ct = 0; ct < 4; ++ct)
      acc[ct] = __builtin_amdgcn_mfma_f32_16x16x32_bf16(Af, Bf[ksl][ct], acc[ct], 0, 0, 0);
  }
#pragma unroll
  for (int ct = 0; ct < 4; ++ct)
#pragma unroll
    for (int reg = 0; reg < 4; ++reg)
      red[w][hi * 4 + reg][ct * 16 + li] = acc[ct][reg];
  __syncthreads();

  int c = l;                       // wave w handles rows {w, w+4, w+8, w+12}, col c
  float atv = atts[c], adv = attd[c];
  float vs[4], vd[4];
#pragma unroll
  for (int i = 0; i < 4; ++i) {
    int r = w + 4 * i;
    float v = red[0][r][c] + red[1][r][c] + red[2][r][c] + red[3][r][c];
    h2bf[(size_t)(brow + r) * HIDC + c] = f2bf(v);
    vs[i] = v * atv; vd[i] = v * adv;
  }
#pragma unroll
  for (int off = 32; off; off >>= 1) {
#pragma unroll
    for (int i = 0; i < 4; ++i) { vs[i] += __shfl_xor(vs[i], off); vd[i] += __shfl_xor(vd[i], off); }
  }
  if (l == 0) {
#pragma unroll
    for (int i = 0; i < 4; ++i) {
      int n = brow + w + 4 * i;
      as2[n] = vs[i]; ad2[n] = vd[i];
    }
  }
}

// ---------------- node2: wave/node, 4-edge-parallel, bf16 h2 gather ---------------------
// lane = e*16 + c : edge slot e, channel block c -> ch c*4..c*4+3
__global__ __launch_bounds__(256) void k_node2(
    const u16* __restrict__ h2bf, const float* __restrict__ as2, const float* __restrict__ ad2,
    const int* __restrict__ rowstart, const int* __restrict__ csr,
    const float* __restrict__ b2, float* __restrict__ out) {
  int n = blockIdx.x * 4 + (threadIdx.x >> 6);
  int lane = threadIdx.x & 63;
  int e = lane >> 4, c = lane & 15;
  int rs = __builtin_amdgcn_readfirstlane(rowstart[n]);
  int re = __builtin_amdgcn_readfirstlane(rowstart[n + 1]);
  float ad = ad2[n];
  float acc[4] = {};
  float zp = 0.f;
  for (int base = rs; base < re; base += 4) {
    int idx = base + e;
    bool ok = idx < re;
    int s = csr[ok ? idx : re - 1];
    float t = as2[s] + ad;
    t = (t > 0.f) ? t : SLOPE * t;
    float pv = __expf(t);
    float p = ok ? pv : 0.f;
    zp += p;
    const u32* hp = (const u32*)(h2bf + (size_t)s * HIDC + c * 4);
    u32 w0 = hp[0], w1 = hp[1];
    acc[0] = fmaf(p, bflo(w0), acc[0]);
    acc[1] = fmaf(p, bfhi(w0), acc[1]);
    acc[2] = fmaf(p, bflo(w1), acc[2]);
    acc[3] = fmaf(p, bfhi(w1), acc[3]);
  }
  zp += __shfl_xor(zp, 16); zp += __shfl_xor(zp, 32);
#pragma unroll
  for (int q = 0; q < 4; ++q) {
    acc[q] += __shfl_xor(acc[q], 16);
    acc[q] += __shfl_xor(acc[q], 32);
  }
  if (e == 0) {
    float inv = 1.f / (zp + SMEPS);
    float4 bv = *(const float4*)(b2 + c * 4);
    float4 o;
    o.x = acc[0] * inv + bv.x; o.y = acc[1] * inv + bv.y;
    o.z = acc[2] * inv + bv.z; o.w = acc[3] * inv + bv.w;
    *(float4*)(out + (size_t)n * HIDC + c * 4) = o;
  }
}

// ---------------- mean pool: block = (graph, 128-ch chunk) ------------------------------
__device__ inline int lowerb(const int* a, int n, int v) {
  int lo = 0, hi = n;
  while (lo < hi) { int mid = (lo + hi) >> 1; if (a[mid] < v) lo = mid + 1; else hi = mid; }
  return lo;
}

__global__ __launch_bounds__(256) void k_pool(const u16* __restrict__ xmb,
                                              const int* __restrict__ batch,
                                              float* __restrict__ out) {
  __shared__ float red[4][128];
  int g = blockIdx.x >> 2;
  int cb = blockIdx.x & 3;          // 128-ch chunk
  int tid = threadIdx.x;
  int c2 = tid & 63;                // 2 ch via u32
  int rq = tid >> 6;
  int lo = lowerb(batch, NN, g);
  int hi = lowerb(batch, NN, g + 1);
  float sx = 0.f, sy = 0.f;
  for (int n = lo + rq; n < hi; n += 4) {
    u32 w = *(const u32*)(xmb + (size_t)n * HC + cb * 128 + c2 * 2);
    sx += bflo(w); sy += bfhi(w);
  }
  red[rq][c2 * 2] = sx; red[rq][c2 * 2 + 1] = sy;
  __syncthreads();
  if (rq == 0) {
    float inv = 1.f / fmaxf((float)(hi - lo), 1.f);
    float vx = red[0][c2 * 2] + red[1][c2 * 2] + red[2][c2 * 2] + red[3][c2 * 2];
    float vy = red[0][c2 * 2 + 1] + red[1][c2 * 2 + 1] + red[2][c2 * 2 + 1] + red[3][c2 * 2 + 1];
    float2 o; o.x = vx * inv; o.y = vy * inv;
    *(float2*)(out + (size_t)g * HC + cb * 128 + c2 * 2) = o;
  }
}

extern "C" void kernel_launch(void* const* d_in, const int* in_sizes, int n_in,
                              void* d_out, int out_size, void* d_ws, size_t ws_size,
                              hipStream_t stream) {
  const float* x     = (const float*)d_in[0];
  const int*   ei    = (const int*)d_in[1];
  const int*   batch = (const int*)d_in[2];
  const float* W1    = (const float*)d_in[3];
  const float* atts1 = (const float*)d_in[4];
  const float* attd1 = (const float*)d_in[5];
  const float* b1    = (const float*)d_in[6];
  const float* W2    = (const float*)d_in[7];
  const float* atts2 = (const float*)d_in[8];
  const float* attd2 = (const float*)d_in[9];
  const float* b2    = (const float*)d_in[10];
  float* out = (float*)d_out;

  float* ws = (float*)d_ws;
  size_t off = 0;
  u16*  aggbf  = (u16*)(ws + off); off += (size_t)NH * NN * INCH / 2;   // bf16 [8][20000][128]
  u16*  xmidbf = (u16*)(ws + off); off += (size_t)NN * HC / 2;          // bf16 [20000][512]
  u16*  h2bf   = (u16*)(ws + off); off += (size_t)NN * HIDC / 2;        // bf16 [20000][64]
  float* al1  = ws + off; off += (size_t)NN * 16;
  float* as2  = ws + off; off += NN;
  float* ad2  = ws + off; off += NN;
  u16*  W1bf  = (u16*)(ws + off); off += 65536 / 2;
  u16*  W2bf  = (u16*)(ws + off); off += 32768 / 2;
  float* wB1  = ws + off; off += 2048;
  u16*  xbf   = (u16*)(ws + off); off += (size_t)NN * INCH / 2;         // bf16 [20000][128]
  int* deg      = (int*)(ws + off); off += NN;
  int* wcur     = (int*)(ws + off); off += NN;
  int* rowstart = (int*)(ws + off); off += NN + 4;
  int* csr      = (int*)(ws + off); off += ETOT;

  hipMemsetAsync(deg, 0, sizeof(int) * 2 * NN, stream);
  k_prep<<<10392, 256, 0, stream>>>(W1, W2, atts1, attd1, x, W1bf, W2bf, wB1, xbf);
  k_hist<<<(ETOT + 255) / 256, 256, 0, stream>>>(ei, deg);
  k_scan<<<1, 1024, 0, stream>>>(deg, rowstart);
  k_fill<<<(ETOT + 255) / 256, 256, 0, stream>>>(ei, rowstart, wcur, csr);

  k_logits1<<<313, 256, 0, stream>>>(x, wB1, al1);
  k_agg1<<<5000, 256, 0, stream>>>(xbf, al1, rowstart, csr, aggbf);
  k_gemm1h<<<313 * 8, 256, 0, stream>>>(aggbf, W1bf, b1, xmidbf);
  k_pool<<<GG * 4, 256, 0, stream>>>(xmidbf, batch, out);
  k_gemm2<<<1250, 256, 0, stream>>>(xmidbf, W2bf, atts2, attd2, h2bf, as2, ad2);
  k_node2<<<5000, 256, 0, stream>>>(h2bf, as2, ad2, rowstart, csr, b2, out + (size_t)GG * HC);
}